// Round 4
// baseline (285.312 us; speedup 1.0000x reference)
//
#include <hip/hip_runtime.h>
#include <hip/hip_fp16.h>
#include <math.h>

#define B_ 4
#define S_ 8192
#define D_ 512
#define H_ 8
#define U_ 45            // int(5*ln(8193)) = 45
#define NCHUNK 16        // 512 keys per attention block

typedef unsigned short ushortT;
typedef __attribute__((ext_vector_type(8))) _Float16 half8;
typedef __attribute__((ext_vector_type(4))) float f32x4;

__device__ __forceinline__ ushortT f2h(float f) {
    return __half_as_ushort(__float2half(f));    // RNE
}
__device__ __forceinline__ float h2f(ushortT u) {
    return __half2float(__ushort_as_half(u));
}

__device__ __forceinline__ void gload_lds16(const ushortT* g, ushortT* l) {
    __builtin_amdgcn_global_load_lds(
        (const __attribute__((address_space(1))) void*)g,
        (__attribute__((address_space(3))) void*)l,
        16, 0, 0);
}

// ---------------------------------------------------------------------------
// Fused pre-pass: blocks [0,8192): X fp32 -> fp16 (block 0 zeroes vsum +
// outbase).  Blocks [8192, 8960): weight transpose+convert WT[n][k]=W[k][n].
// ---------------------------------------------------------------------------
__global__ __launch_bounds__(256) void prep_kernel(
    const float* __restrict__ X, ushortT* __restrict__ Xf,
    const float* __restrict__ Wq, const float* __restrict__ Wk,
    const float* __restrict__ Wv,
    ushortT* __restrict__ WqT, ushortT* __restrict__ WkT,
    ushortT* __restrict__ WvT,
    float* __restrict__ vsum, float* __restrict__ outbase)
{
    __shared__ float t[32][33];
    const int bx = blockIdx.x;
    if (bx < 8192) {
        if (bx == 0) {
            float4 z = {0.f, 0.f, 0.f, 0.f};
            *(float4*)&vsum[threadIdx.x * 8]        = z;
            *(float4*)&vsum[threadIdx.x * 8 + 4]    = z;
            *(float4*)&outbase[threadIdx.x * 8]     = z;
            *(float4*)&outbase[threadIdx.x * 8 + 4] = z;
        }
        size_t i = ((size_t)bx * 256 + threadIdx.x) * 8;
        float4 a = *(const float4*)(X + i);
        float4 b = *(const float4*)(X + i + 4);
        *(ushort4*)(Xf + i)     = make_ushort4(f2h(a.x), f2h(a.y), f2h(a.z), f2h(a.w));
        *(ushort4*)(Xf + i + 4) = make_ushort4(f2h(b.x), f2h(b.y), f2h(b.z), f2h(b.w));
    } else {
        const int idx = bx - 8192;
        const int z = idx >> 8, rem = idx & 255;
        const int r0 = (rem >> 4) * 32, c0 = (rem & 15) * 32;
        const float* W = (z == 0) ? Wq : (z == 1) ? Wk : Wv;
        ushortT* O = (z == 0) ? WqT : (z == 1) ? WkT : WvT;
        const int tx = threadIdx.x & 31, ty4 = (threadIdx.x >> 5) * 4;
#pragma unroll
        for (int i = 0; i < 4; ++i)
            t[ty4 + i][tx] = W[(size_t)(r0 + ty4 + i) * 512 + c0 + tx];
        __syncthreads();
#pragma unroll
        for (int i = 0; i < 4; ++i)
            O[(size_t)(c0 + ty4 + i) * 512 + r0 + tx] = f2h(t[tx][ty4 + i]);
    }
}

// ---------------------------------------------------------------------------
// MFMA QKV projection, fp16, BK=64, single-buffered 2-barrier loop.
// R12 wave-split stream fusion (verified: 83.2us, MfmaUtil 25.7, FETCH 55.5MB):
//   y 0-3 (fused QK): one 128-row Xf A-tile staged ONCE, waves 0-3 Q-tile,
//     waves 4-7 K-tile.  y 4-5 (V): A = WvT 256 rows, B = Xf 128 rows.
// R13: Q-stream no longer stores Qbuf (32MB of writes for 184KB of reads) —
//   only sparsity.  Selected Q rows are recomputed in topk_kernel.
// LDS 48KB, 2 blocks/CU.  8-chunk rotate swizzle: 0 conflicts.
// ---------------------------------------------------------------------------
__global__ __launch_bounds__(512, 2) void qkv_mfma(
    const ushortT* __restrict__ Xf,
    const ushortT* __restrict__ WqT, const ushortT* __restrict__ WkT,
    const ushortT* __restrict__ WvT,
    const float* __restrict__ bq, const float* __restrict__ bk,
    const float* __restrict__ bv,
    ushortT* __restrict__ Kbuf, ushortT* __restrict__ VT,
    float* __restrict__ sparsity, float* __restrict__ vsum)
{
    __shared__ ushortT lds[3 * 128 * 64];   // 48KB: A | B0 | B1 (16KB each)

    const int tid  = threadIdx.x;
    const int w    = tid >> 6, lane = tid & 63;
    const int quad = lane >> 4, c16 = lane & 15;
    const bool fusedQK = (blockIdx.y < 4);
    const int stream = w >> 2;               // QK: 0=Q wave, 1=K wave
    const int aw   = fusedQK ? ((w >> 1) & 1) : (w >> 1);  // A-dir wave idx
    const int bw   = w & 1;                                 // B-dir wave idx
    const int m0   = blockIdx.x * 128;
    const int n0   = fusedQK ? (blockIdx.y * 128) : ((blockIdx.y - 4) * 256);

    const int srowL = lane >> 3;                            // 0..7 within wave
    const int slc   = (((lane & 7) - (srowL & 7)) & 7) * 8; // swizzled src chunk
    const int rrot  = c16 & 7;

    const ushortT* Brd = fusedQK ? (lds + 8192 + stream * 8192) : (lds + 16384);
    const int awBase = aw * 64;
    const int bwBase = bw * 64;

    f32x4 acc[4][4];
#pragma unroll
    for (int i = 0; i < 4; ++i)
#pragma unroll
        for (int j = 0; j < 4; ++j) acc[i][j] = (f32x4){0.f, 0.f, 0.f, 0.f};

    for (int k0 = 0; k0 < 512; k0 += 64) {
        __syncthreads();
        if (fusedQK) {
#pragma unroll
            for (int c = 0; c < 2; ++c) {
                const int R  = c * 64 + w * 8 + srowL;
                const int lb = c * 4096 + w * 512;
                gload_lds16(Xf  + (size_t)(m0 + R) * 512 + k0 + slc, lds + lb);
                gload_lds16(WqT + (size_t)(n0 + R) * 512 + k0 + slc, lds + 8192 + lb);
                gload_lds16(WkT + (size_t)(n0 + R) * 512 + k0 + slc, lds + 16384 + lb);
            }
        } else {
#pragma unroll
            for (int c = 0; c < 4; ++c) {
                const int R = c * 64 + w * 8 + srowL;
                gload_lds16(WvT + (size_t)(n0 + R) * 512 + k0 + slc,
                            lds + c * 4096 + w * 512);
            }
#pragma unroll
            for (int c = 0; c < 2; ++c) {
                const int R = c * 64 + w * 8 + srowL;
                gload_lds16(Xf + (size_t)(m0 + R) * 512 + k0 + slc,
                            lds + 16384 + c * 4096 + w * 512);
            }
        }
        __syncthreads();
#pragma unroll
        for (int kk = 0; kk < 2; ++kk) {
            const int phk = (((kk * 4 + quad) + rrot) & 7) * 8;
            half8 af[4], bf[4];
#pragma unroll
            for (int i = 0; i < 4; ++i) {
                af[i] = *(const half8*)&lds[(awBase + i * 16 + c16) * 64 + phk];
                bf[i] = *(const half8*)&Brd[(bwBase + i * 16 + c16) * 64 + phk];
            }
#pragma unroll
            for (int i = 0; i < 4; ++i)
#pragma unroll
                for (int j = 0; j < 4; ++j)
                    acc[i][j] = __builtin_amdgcn_mfma_f32_16x16x32_f16(af[i], bf[j], acc[i][j], 0, 0, 0);
        }
    }

    // ---- epilogue ----
    const int b = m0 >> 13;
    if (fusedQK && stream == 0) {
        // Q: sparsity only (sum of squares per row); no Qbuf store.
        const int head = (n0 + bw * 64) >> 6;
        float bb[4];
#pragma unroll
        for (int j = 0; j < 4; ++j) bb[j] = bq[n0 + bw * 64 + j * 16 + c16];
#pragma unroll
        for (int i = 0; i < 4; ++i)
#pragma unroll
            for (int r = 0; r < 4; ++r) {
                const int s = (m0 & 8191) + awBase + i * 16 + quad * 4 + r;
                float p = 0.f;
#pragma unroll
                for (int j = 0; j < 4; ++j) {
                    float v = acc[i][j][r] + bb[j];
                    p = fmaf(v, v, p);
                }
                p += __shfl_xor(p, 1);
                p += __shfl_xor(p, 2);
                p += __shfl_xor(p, 4);
                p += __shfl_xor(p, 8);
                if (c16 == 0)
                    sparsity[((size_t)b * H_ + head) * S_ + s] = p;
            }
    } else if (fusedQK) {
        const int head = (n0 + bw * 64) >> 6;
        float bb[4];
#pragma unroll
        for (int j = 0; j < 4; ++j) bb[j] = bk[n0 + bw * 64 + j * 16 + c16];
        ushortT* kbase = Kbuf + ((size_t)(b * 8 + head) * 8192) * 64;
#pragma unroll
        for (int i = 0; i < 4; ++i)
#pragma unroll
            for (int r = 0; r < 4; ++r) {
                const int s = (m0 & 8191) + awBase + i * 16 + quad * 4 + r;
#pragma unroll
                for (int j = 0; j < 4; ++j)
                    kbase[(size_t)s * 64 + j * 16 + c16] = f2h(acc[i][j][r] + bb[j]);
            }
    } else {
        // V transposed: VT[((b*8+head)*64 + dd)*8192 + s]
        const int sbase = (m0 & 8191) + bwBase;
#pragma unroll
        for (int i = 0; i < 4; ++i)
#pragma unroll
            for (int r = 0; r < 4; ++r) {
                const int dcol = n0 + awBase + i * 16 + quad * 4 + r;
                const int head = dcol >> 6, dd = dcol & 63;
                const float biasv = bv[dcol];
                ushortT* vrow = VT + ((size_t)(b * 8 + head) * 64 + dd) * 8192;
                float vsa = 0.f;
#pragma unroll
                for (int j = 0; j < 4; ++j) {
                    float v = acc[i][j][r] + biasv;
                    vrow[sbase + j * 16 + c16] = f2h(v);
                    vsa += v;
                }
                vsa += __shfl_xor(vsa, 1);
                vsa += __shfl_xor(vsa, 2);
                vsa += __shfl_xor(vsa, 4);
                vsa += __shfl_xor(vsa, 8);
                if (c16 == 0) atomicAdd(&vsum[b * 512 + dcol], vsa);
            }
    }
}

// ---------------------------------------------------------------------------
// Blocks [0,32): top-45 per (b,h) via 4-level byte radix-select, THEN
//   recompute the 45 selected Q rows (48x64x512 MFMA GEMM, A = gathered Xf
//   rows in LDS, B = WqT) and store pre-scaled fp16 selQ[bh][48][64].
//   Phase-2 LDS (selX, 45 rows padded to 520 halves: +16B pad -> 2-way bank
//   alias max) reuses the radix-select region after a barrier.
// Blocks [32,64): outbase partial: outbase[b] += bo (ks==0) + k-slice
//   of mean_flat[b] @ Wo  (b = idx>>3, ks = (idx&7)>>1, d-half = idx&1).
// ---------------------------------------------------------------------------
__global__ __launch_bounds__(256) void topk_kernel(
    const float* __restrict__ sparsity, int* __restrict__ topidx,
    const float* __restrict__ vsum, const float* __restrict__ Wo,
    const float* __restrict__ bo, float* __restrict__ outbase,
    const ushortT* __restrict__ Xf, const ushortT* __restrict__ WqT,
    const float* __restrict__ bq, ushortT* __restrict__ selQ)
{
    __shared__ __align__(16) char smem[49920];
    unsigned* vals        = (unsigned*)smem;                    // 32KB
    unsigned (*hist)[256] = (unsigned (*)[256])(smem + 32768);  // 8KB
    int* ssum             = (int*)(smem + 40960);               // 1KB
    int* eqidx            = (int*)(smem + 41984);               // 256B
    ushortT* selX         = (ushortT*)smem;                     // phase 2: 49,920B
    __shared__ unsigned prefix_s;
    __shared__ int need_s;
    __shared__ int cnt_gt_s, cnt_eq_s;
    const int tid = threadIdx.x;

    if (blockIdx.x >= 32) {
        const int idx = blockIdx.x - 32;
        const int b = idx >> 3, ks = (idx & 7) >> 1, dh = idx & 1;
        const int d = dh * 256 + tid;
        float acc = (ks == 0) ? bo[d] : 0.f;
        const int r0 = ks * 128;
        for (int r = r0; r < r0 + 128; ++r) {
            float mv = vsum[b * 512 + r] * (1.0f / S_);
            acc = fmaf(mv, Wo[(size_t)r * 512 + d], acc);
        }
        atomicAdd(&outbase[b * 512 + d], acc);
        return;
    }

    const int bh = blockIdx.x;
    const unsigned* sp = (const unsigned*)(sparsity + (size_t)bh * S_);
    for (int i = tid; i < S_; i += 256) vals[i] = sp[i];

    unsigned prefix = 0;
    int need = U_;
    const int rep = tid & 7;
    for (int level = 0; level < 4; ++level) {
        const int shift = 24 - level * 8;
#pragma unroll
        for (int r = 0; r < 8; ++r) hist[r][tid] = 0;
        __syncthreads();
        const unsigned pmask = (level == 0) ? 0u : (0xFFFFFFFFu << (shift + 8));
        for (int i = tid; i < S_; i += 256) {
            unsigned v = vals[i];
            if ((v & pmask) == prefix)
                atomicAdd(&hist[rep][(v >> shift) & 255], 1u);
        }
        __syncthreads();
        int bs = 0;
#pragma unroll
        for (int r = 0; r < 8; ++r) bs += (int)hist[r][tid];
        ssum[tid] = bs;
        __syncthreads();
        for (int off = 1; off < 256; off <<= 1) {
            int add = (tid + off < 256) ? ssum[tid + off] : 0;
            __syncthreads();
            ssum[tid] += add;
            __syncthreads();
        }
        int snext = (tid == 255) ? 0 : ssum[tid + 1];
        if (ssum[tid] >= need && snext < need) {
            prefix_s = prefix | ((unsigned)tid << shift);
            need_s = need - snext;
        }
        __syncthreads();
        prefix = prefix_s;
        need = need_s;
        __syncthreads();
    }
    const unsigned T = prefix;
    if (tid == 0) { cnt_gt_s = 0; cnt_eq_s = 0; }
    __syncthreads();
    for (int i = tid; i < S_; i += 256) {
        unsigned v = vals[i];
        if (v > T) {
            int p = atomicAdd(&cnt_gt_s, 1);
            topidx[bh * U_ + p] = i;
        } else if (v == T) {
            int p = atomicAdd(&cnt_eq_s, 1);
            if (p < 64) eqidx[p] = i;
        }
    }
    __syncthreads();
    if (tid == 0) {
        int rem = U_ - cnt_gt_s;
        int n = cnt_eq_s < 64 ? cnt_eq_s : 64;
        for (int a = 0; a < rem; ++a) {     // smallest indices among ties
            int best = 1 << 30, bj = 0;
            for (int j = 0; j < n; ++j)
                if (eqidx[j] < best) { best = eqidx[j]; bj = j; }
            topidx[bh * U_ + cnt_gt_s + a] = best;
            eqidx[bj] = 1 << 30;
        }
    }
    __syncthreads();               // topidx final; region A free for reuse

    // ---- phase 2: selQ = (Xf[sel] @ WqT^T + bq) * 0.125, fp16 ----
    const int b = bh >> 3, h = bh & 7;
    for (int i = tid; i < 48 * 64; i += 256) {
        const int row = i >> 6, ch = i & 63;
        half8 v;
#pragma unroll
        for (int z = 0; z < 8; ++z) v[z] = (_Float16)0.0f;
        if (row < U_) {
            const int s = topidx[bh * U_ + row];
            v = *(const half8*)&Xf[((size_t)b * 8192 + s) * 512 + ch * 8];
        }
        *(half8*)&selX[row * 520 + ch * 8] = v;
    }
    __syncthreads();

    const int w = tid >> 6, lane = tid & 63;
    const int quad = lane >> 4, c16 = lane & 15;
    f32x4 qacc[3];
#pragma unroll
    for (int mt = 0; mt < 3; ++mt) qacc[mt] = (f32x4){0.f, 0.f, 0.f, 0.f};
    const ushortT* brow = WqT + (size_t)(h * 64 + w * 16 + c16) * 512;
    for (int k0 = 0; k0 < 512; k0 += 32) {
        half8 bf = *(const half8*)&brow[k0 + quad * 8];
#pragma unroll
        for (int mt = 0; mt < 3; ++mt) {
            half8 af = *(const half8*)&selX[(mt * 16 + c16) * 520 + k0 + quad * 8];
            qacc[mt] = __builtin_amdgcn_mfma_f32_16x16x32_f16(af, bf, qacc[mt], 0, 0, 0);
        }
    }
    const float bb = bq[h * 64 + w * 16 + c16];
    ushortT* oq = selQ + (size_t)bh * 48 * 64 + (w * 16 + c16);
#pragma unroll
    for (int mt = 0; mt < 3; ++mt)
#pragma unroll
        for (int r = 0; r < 4; ++r) {
            const int m = mt * 16 + quad * 4 + r;
            float v = (m < U_) ? (qacc[mt][r] + bb) * 0.125f : 0.f;
            oq[(size_t)m * 64] = f2h(v);
        }
}

// ---------------------------------------------------------------------------
// MFMA attention partials (fp16), no-max softmax (|s| bounded ~4).
// Grid (NCHUNK + 512, 32 bh), 256 thr.
//   x < 16:  attention, block = 512 keys, 4 chunks of 128.  Q fragments
//            loaded directly from selQ (pre-scaled, L2-hot, 6KB/bh).
//   x >= 16: broadcast fill out[b,s,:] = outbase[b,:] (merged from the old
//            fill_kernel — rides in the occupancy holes of the latency-bound
//            attn blocks; needs only outbase,写 disjoint from attn outputs).
// ---------------------------------------------------------------------------
__global__ __launch_bounds__(256, 2) void attn_mfma(
    const ushortT* __restrict__ selQ, const ushortT* __restrict__ Kbuf,
    const ushortT* __restrict__ VT,
    float* __restrict__ pl, float* __restrict__ pacc,
    const float* __restrict__ outbase, float* __restrict__ out)
{
    __shared__ float sc[48 * 132];          // scores f32; P fp16 in-place

    const int tid = threadIdx.x;

    if (blockIdx.x >= NCHUNK) {
        const int unit = (blockIdx.x - NCHUNK) * 32 + blockIdx.y;
        size_t e0 = ((size_t)unit * 256 + tid) * 4;
        int b = (int)(e0 >> 22);          // 8192*512 = 2^22
        int col = (int)(e0 & 511);
        float4 v = *(const float4*)&outbase[b * 512 + col];
        *(float4*)&out[e0] = v;
        return;
    }

    const int w = tid >> 6, lane = tid & 63;
    const int quad = lane >> 4, c16 = lane & 15;
    const int bh = blockIdx.y;
    const int s_base = blockIdx.x * 512;

    f32x4 O[3];
#pragma unroll
    for (int mt = 0; mt < 3; ++mt) O[mt] = (f32x4){0.f, 0.f, 0.f, 0.f};
    float lacc[12];
#pragma unroll
    for (int qi = 0; qi < 12; ++qi) lacc[qi] = 0.f;

    const ushortT* sq = selQ + (size_t)bh * 48 * 64;
    half8 qa[3][2];
#pragma unroll
    for (int mt = 0; mt < 3; ++mt)
#pragma unroll
        for (int kk = 0; kk < 2; ++kk)
            qa[mt][kk] = *(const half8*)&sq[(mt * 16 + c16) * 64 + kk * 32 + quad * 8];

    const ushortT* kb  = Kbuf + (size_t)bh * 8192 * 64;
    const ushortT* vtb = VT + ((size_t)bh * 64 + w * 16 + c16) * 8192;

    for (int ci = 0; ci < 4; ++ci) {
        const int s0 = s_base + ci * 128;

        half8 kf[2][2];
#pragma unroll
        for (int nt2 = 0; nt2 < 2; ++nt2)
#pragma unroll
            for (int kk = 0; kk < 2; ++kk)
                kf[nt2][kk] = *(const half8*)&kb[
                    (size_t)(s0 + w * 32 + nt2 * 16 + c16) * 64 + kk * 32 + quad * 8];
        f32x4 sacc[3][2];
#pragma unroll
        for (int mt = 0; mt < 3; ++mt)
#pragma unroll
            for (int nt2 = 0; nt2 < 2; ++nt2) {
                sacc[mt][nt2] = (f32x4){0.f, 0.f, 0.f, 0.f};
#pragma unroll
                for (int kk = 0; kk < 2; ++kk)
                    sacc[mt][nt2] = __builtin_amdgcn_mfma_f32_16x16x32_f16(
                        qa[mt][kk], kf[nt2][kk], sacc[mt][nt2], 0, 0, 0);
            }
#pragma unroll
        for (int mt = 0; mt < 3; ++mt)
#pragma unroll
            for (int nt2 = 0; nt2 < 2; ++nt2)
#pragma unroll
                for (int r = 0; r < 4; ++r)
                    sc[(mt * 16 + quad * 4 + r) * 132 + w * 32 + nt2 * 16 + c16] =
                        sacc[mt][nt2][r];
        __syncthreads();

        half8 vb[4];
#pragma unroll
        for (int kk = 0; kk < 4; ++kk)
            vb[kk] = *(const half8*)&vtb[s0 + kk * 32 + quad * 8];

#pragma unroll
        for (int qi = 0; qi < 12; ++qi) {
            const int q = w * 12 + qi;
            float x0 = sc[q * 132 + lane];
            float x1 = sc[q * 132 + 64 + lane];
            ushortT u0 = f2h(__expf(x0));
            ushortT u1 = f2h(__expf(x1));
            lacc[qi] += h2f(u0) + h2f(u1);
            ushortT* pr = (ushortT*)&sc[q * 132];
            pr[lane] = u0;
            pr[lane + 64] = u1;
        }
        __syncthreads();

#pragma unroll
        for (int mt = 0; mt < 3; ++mt)
#pragma unroll
            for (int kk = 0; kk < 4; ++kk) {
                half8 pa = *(const half8*)((const ushortT*)sc +
                    (size_t)(mt * 16 + c16) * 264 + kk * 32 + quad * 8);
                O[mt] = __builtin_amdgcn_mfma_f32_16x16x32_f16(pa, vb[kk], O[mt], 0, 0, 0);
            }
        __syncthreads();
    }

#pragma unroll
    for (int mt = 0; mt < 3; ++mt)
#pragma unroll
        for (int r = 0; r < 4; ++r) {
            const int q = mt * 16 + quad * 4 + r;
            if (q < U_)
                pacc[(((size_t)bh * NCHUNK + blockIdx.x) * U_ + q) * 64 + w * 16 + c16] =
                    O[mt][r];
        }
#pragma unroll
    for (int qi = 0; qi < 12; ++qi) {
        const int q = w * 12 + qi;
        float ssum = lacc[qi];
#pragma unroll
        for (int off = 1; off < 64; off <<= 1) ssum += __shfl_xor(ssum, off);
        if (lane == 0 && q < U_)
            pl[((size_t)bh * NCHUNK + blockIdx.x) * U_ + q] = ssum;
    }
}

// ---------------------------------------------------------------------------
// Merged combine + correction: block (q, bh).
// ---------------------------------------------------------------------------
__global__ __launch_bounds__(512) void corr_out_kernel(
    const float* __restrict__ pl, const float* __restrict__ pacc,
    const float* __restrict__ vsum, const float* __restrict__ Wo,
    const int* __restrict__ topidx, float* __restrict__ out)
{
    __shared__ float corrS[64];
    const int q = blockIdx.x, bh = blockIdx.y;
    const int b = bh >> 3, h = bh & 7, tid = threadIdx.x;
    if (tid < 64) {
        float L = 0.f, a = 0.f;
        for (int c = 0; c < NCHUNK; ++c) {
            L += pl[((size_t)bh * NCHUNK + c) * U_ + q];
            a += pacc[(((size_t)bh * NCHUNK + c) * U_ + q) * 64 + tid];
        }
        corrS[tid] = a / L - vsum[b * 512 + h * 64 + tid] * (1.0f / S_);
    }
    __syncthreads();
    const int s = topidx[bh * U_ + q];
    const int d = tid;
    float delta = 0.f;
#pragma unroll
    for (int r = 0; r < 64; ++r)
        delta = fmaf(corrS[r], Wo[(size_t)(h * 64 + r) * 512 + d], delta);
    atomicAdd(&out[((size_t)b * S_ + s) * 512 + d], delta);
}

// ---------------------------------------------------------------------------
extern "C" void kernel_launch(void* const* d_in, const int* in_sizes, int n_in,
                              void* d_out, int out_size, void* d_ws, size_t ws_size,
                              hipStream_t stream)
{
    const float* X  = (const float*)d_in[0];
    const float* Wq = (const float*)d_in[1];
    const float* bq = (const float*)d_in[2];
    const float* Wk = (const float*)d_in[3];
    const float* bk = (const float*)d_in[4];
    const float* Wv = (const float*)d_in[5];
    const float* bv = (const float*)d_in[6];
    const float* Wo = (const float*)d_in[7];
    const float* bo = (const float*)d_in[8];
    float* out = (float*)d_out;

    char* ws = (char*)d_ws;
    size_t off = 0;
    auto alloc = [&](size_t bytes) {
        void* p = ws + off;
        off = (off + bytes + 255) & ~(size_t)255;
        return p;
    };
    ushortT* Xf   = (ushortT*)alloc((size_t)B_ * S_ * D_ * 2);
    ushortT* Kbuf = (ushortT*)alloc((size_t)B_ * S_ * D_ * 2);
    ushortT* VT   = (ushortT*)alloc((size_t)B_ * S_ * D_ * 2);
    ushortT* WqT  = (ushortT*)alloc((size_t)D_ * D_ * 2);
    ushortT* WkT  = (ushortT*)alloc((size_t)D_ * D_ * 2);
    ushortT* WvT  = (ushortT*)alloc((size_t)D_ * D_ * 2);
    ushortT* selQ = (ushortT*)alloc((size_t)B_ * H_ * 48 * 64 * 2);
    float* sparsity = (float*)alloc((size_t)B_ * H_ * S_ * 4);
    int*   topidx   = (int*)alloc((size_t)B_ * H_ * U_ * 4);
    float* pl       = (float*)alloc((size_t)B_ * H_ * NCHUNK * U_ * 4);
    float* pacc     = (float*)alloc((size_t)B_ * H_ * NCHUNK * U_ * 64 * 4);
    float* vsum     = (float*)alloc((size_t)B_ * 512 * 4);
    float* outbase  = (float*)alloc((size_t)B_ * 512 * 4);

    prep_kernel<<<8960, 256, 0, stream>>>(X, Xf, Wq, Wk, Wv, WqT, WkT, WvT,
                                          vsum, outbase);
    qkv_mfma<<<dim3(256, 6), 512, 0, stream>>>(Xf, WqT, WkT, WvT,
                                               bq, bk, bv, Kbuf, VT,
                                               sparsity, vsum);
    topk_kernel<<<64, 256, 0, stream>>>(sparsity, topidx, vsum, Wo, bo, outbase,
                                        Xf, WqT, bq, selQ);
    attn_mfma<<<dim3(NCHUNK + 512, B_ * H_), 256, 0, stream>>>(
        selQ, Kbuf, VT, pl, pacc, outbase, out);
    corr_out_kernel<<<dim3(U_, B_ * H_), 512, 0, stream>>>(pl, pacc, vsum, Wo,
                                                           topidx, out);
}

// Round 5
// 276.715 us; speedup vs baseline: 1.0311x; 1.0311x over previous
//
#include <hip/hip_runtime.h>
#include <hip/hip_fp16.h>
#include <math.h>

#define B_ 4
#define S_ 8192
#define D_ 512
#define H_ 8
#define U_ 45            // int(5*ln(8193)) = 45
#define NCHUNK 32        // 256 keys per attention block (R14: was 16)

typedef unsigned short ushortT;
typedef __attribute__((ext_vector_type(8))) _Float16 half8;
typedef __attribute__((ext_vector_type(4))) float f32x4;

__device__ __forceinline__ ushortT f2h(float f) {
    return __half_as_ushort(__float2half(f));    // RNE
}
__device__ __forceinline__ float h2f(ushortT u) {
    return __half2float(__ushort_as_half(u));
}

__device__ __forceinline__ void gload_lds16(const ushortT* g, ushortT* l) {
    __builtin_amdgcn_global_load_lds(
        (const __attribute__((address_space(1))) void*)g,
        (__attribute__((address_space(3))) void*)l,
        16, 0, 0);
}

// ---------------------------------------------------------------------------
// Fused pre-pass: blocks [0,8192): X fp32 -> fp16 (block 0 zeroes vsum +
// outbase).  Blocks [8192, 8960): weight transpose+convert WT[n][k]=W[k][n].
// ---------------------------------------------------------------------------
__global__ __launch_bounds__(256) void prep_kernel(
    const float* __restrict__ X, ushortT* __restrict__ Xf,
    const float* __restrict__ Wq, const float* __restrict__ Wk,
    const float* __restrict__ Wv,
    ushortT* __restrict__ WqT, ushortT* __restrict__ WkT,
    ushortT* __restrict__ WvT,
    float* __restrict__ vsum, float* __restrict__ outbase)
{
    __shared__ float t[32][33];
    const int bx = blockIdx.x;
    if (bx < 8192) {
        if (bx == 0) {
            float4 z = {0.f, 0.f, 0.f, 0.f};
            *(float4*)&vsum[threadIdx.x * 8]        = z;
            *(float4*)&vsum[threadIdx.x * 8 + 4]    = z;
            *(float4*)&outbase[threadIdx.x * 8]     = z;
            *(float4*)&outbase[threadIdx.x * 8 + 4] = z;
        }
        size_t i = ((size_t)bx * 256 + threadIdx.x) * 8;
        float4 a = *(const float4*)(X + i);
        float4 b = *(const float4*)(X + i + 4);
        *(ushort4*)(Xf + i)     = make_ushort4(f2h(a.x), f2h(a.y), f2h(a.z), f2h(a.w));
        *(ushort4*)(Xf + i + 4) = make_ushort4(f2h(b.x), f2h(b.y), f2h(b.z), f2h(b.w));
    } else {
        const int idx = bx - 8192;
        const int z = idx >> 8, rem = idx & 255;
        const int r0 = (rem >> 4) * 32, c0 = (rem & 15) * 32;
        const float* W = (z == 0) ? Wq : (z == 1) ? Wk : Wv;
        ushortT* O = (z == 0) ? WqT : (z == 1) ? WkT : WvT;
        const int tx = threadIdx.x & 31, ty4 = (threadIdx.x >> 5) * 4;
#pragma unroll
        for (int i = 0; i < 4; ++i)
            t[ty4 + i][tx] = W[(size_t)(r0 + ty4 + i) * 512 + c0 + tx];
        __syncthreads();
#pragma unroll
        for (int i = 0; i < 4; ++i)
            O[(size_t)(c0 + ty4 + i) * 512 + r0 + tx] = f2h(t[tx][ty4 + i]);
    }
}

// ---------------------------------------------------------------------------
// MFMA QKV projection, fp16, BK=64, single-buffered 2-barrier loop.
// R12 wave-split stream fusion + R13 no-Qbuf (verified: 78.6us, MfmaUtil
// 27.5, WRITE 70.7MB):
//   y 0-3 (fused QK): one 128-row Xf A-tile staged ONCE, waves 0-3 Q-tile
//     (sparsity only), waves 4-7 K-tile.  y 4-5 (V): A = WvT, B = Xf.
// LDS 48KB, 8-chunk rotate swizzle: 0 conflicts.
// ---------------------------------------------------------------------------
__global__ __launch_bounds__(512, 2) void qkv_mfma(
    const ushortT* __restrict__ Xf,
    const ushortT* __restrict__ WqT, const ushortT* __restrict__ WkT,
    const ushortT* __restrict__ WvT,
    const float* __restrict__ bq, const float* __restrict__ bk,
    const float* __restrict__ bv,
    ushortT* __restrict__ Kbuf, ushortT* __restrict__ VT,
    float* __restrict__ sparsity, float* __restrict__ vsum)
{
    __shared__ ushortT lds[3 * 128 * 64];   // 48KB: A | B0 | B1 (16KB each)

    const int tid  = threadIdx.x;
    const int w    = tid >> 6, lane = tid & 63;
    const int quad = lane >> 4, c16 = lane & 15;
    const bool fusedQK = (blockIdx.y < 4);
    const int stream = w >> 2;               // QK: 0=Q wave, 1=K wave
    const int aw   = fusedQK ? ((w >> 1) & 1) : (w >> 1);  // A-dir wave idx
    const int bw   = w & 1;                                 // B-dir wave idx
    const int m0   = blockIdx.x * 128;
    const int n0   = fusedQK ? (blockIdx.y * 128) : ((blockIdx.y - 4) * 256);

    const int srowL = lane >> 3;                            // 0..7 within wave
    const int slc   = (((lane & 7) - (srowL & 7)) & 7) * 8; // swizzled src chunk
    const int rrot  = c16 & 7;

    const ushortT* Brd = fusedQK ? (lds + 8192 + stream * 8192) : (lds + 16384);
    const int awBase = aw * 64;
    const int bwBase = bw * 64;

    f32x4 acc[4][4];
#pragma unroll
    for (int i = 0; i < 4; ++i)
#pragma unroll
        for (int j = 0; j < 4; ++j) acc[i][j] = (f32x4){0.f, 0.f, 0.f, 0.f};

    for (int k0 = 0; k0 < 512; k0 += 64) {
        __syncthreads();
        if (fusedQK) {
#pragma unroll
            for (int c = 0; c < 2; ++c) {
                const int R  = c * 64 + w * 8 + srowL;
                const int lb = c * 4096 + w * 512;
                gload_lds16(Xf  + (size_t)(m0 + R) * 512 + k0 + slc, lds + lb);
                gload_lds16(WqT + (size_t)(n0 + R) * 512 + k0 + slc, lds + 8192 + lb);
                gload_lds16(WkT + (size_t)(n0 + R) * 512 + k0 + slc, lds + 16384 + lb);
            }
        } else {
#pragma unroll
            for (int c = 0; c < 4; ++c) {
                const int R = c * 64 + w * 8 + srowL;
                gload_lds16(WvT + (size_t)(n0 + R) * 512 + k0 + slc,
                            lds + c * 4096 + w * 512);
            }
#pragma unroll
            for (int c = 0; c < 2; ++c) {
                const int R = c * 64 + w * 8 + srowL;
                gload_lds16(Xf + (size_t)(m0 + R) * 512 + k0 + slc,
                            lds + 16384 + c * 4096 + w * 512);
            }
        }
        __syncthreads();
#pragma unroll
        for (int kk = 0; kk < 2; ++kk) {
            const int phk = (((kk * 4 + quad) + rrot) & 7) * 8;
            half8 af[4], bf[4];
#pragma unroll
            for (int i = 0; i < 4; ++i) {
                af[i] = *(const half8*)&lds[(awBase + i * 16 + c16) * 64 + phk];
                bf[i] = *(const half8*)&Brd[(bwBase + i * 16 + c16) * 64 + phk];
            }
#pragma unroll
            for (int i = 0; i < 4; ++i)
#pragma unroll
                for (int j = 0; j < 4; ++j)
                    acc[i][j] = __builtin_amdgcn_mfma_f32_16x16x32_f16(af[i], bf[j], acc[i][j], 0, 0, 0);
        }
    }

    // ---- epilogue ----
    const int b = m0 >> 13;
    if (fusedQK && stream == 0) {
        // Q: sparsity only (sum of squares per row); no Qbuf store.
        const int head = (n0 + bw * 64) >> 6;
        float bb[4];
#pragma unroll
        for (int j = 0; j < 4; ++j) bb[j] = bq[n0 + bw * 64 + j * 16 + c16];
#pragma unroll
        for (int i = 0; i < 4; ++i)
#pragma unroll
            for (int r = 0; r < 4; ++r) {
                const int s = (m0 & 8191) + awBase + i * 16 + quad * 4 + r;
                float p = 0.f;
#pragma unroll
                for (int j = 0; j < 4; ++j) {
                    float v = acc[i][j][r] + bb[j];
                    p = fmaf(v, v, p);
                }
                p += __shfl_xor(p, 1);
                p += __shfl_xor(p, 2);
                p += __shfl_xor(p, 4);
                p += __shfl_xor(p, 8);
                if (c16 == 0)
                    sparsity[((size_t)b * H_ + head) * S_ + s] = p;
            }
    } else if (fusedQK) {
        const int head = (n0 + bw * 64) >> 6;
        float bb[4];
#pragma unroll
        for (int j = 0; j < 4; ++j) bb[j] = bk[n0 + bw * 64 + j * 16 + c16];
        ushortT* kbase = Kbuf + ((size_t)(b * 8 + head) * 8192) * 64;
#pragma unroll
        for (int i = 0; i < 4; ++i)
#pragma unroll
            for (int r = 0; r < 4; ++r) {
                const int s = (m0 & 8191) + awBase + i * 16 + quad * 4 + r;
#pragma unroll
                for (int j = 0; j < 4; ++j)
                    kbase[(size_t)s * 64 + j * 16 + c16] = f2h(acc[i][j][r] + bb[j]);
            }
    } else {
        // V transposed: VT[((b*8+head)*64 + dd)*8192 + s]
        const int sbase = (m0 & 8191) + bwBase;
#pragma unroll
        for (int i = 0; i < 4; ++i)
#pragma unroll
            for (int r = 0; r < 4; ++r) {
                const int dcol = n0 + awBase + i * 16 + quad * 4 + r;
                const int head = dcol >> 6, dd = dcol & 63;
                const float biasv = bv[dcol];
                ushortT* vrow = VT + ((size_t)(b * 8 + head) * 64 + dd) * 8192;
                float vsa = 0.f;
#pragma unroll
                for (int j = 0; j < 4; ++j) {
                    float v = acc[i][j][r] + biasv;
                    vrow[sbase + j * 16 + c16] = f2h(v);
                    vsa += v;
                }
                vsa += __shfl_xor(vsa, 1);
                vsa += __shfl_xor(vsa, 2);
                vsa += __shfl_xor(vsa, 4);
                vsa += __shfl_xor(vsa, 8);
                if (c16 == 0) atomicAdd(&vsum[b * 512 + dcol], vsa);
            }
    }
}

// ---------------------------------------------------------------------------
// Blocks [0,32): top-45 per (b,h) via 4-level byte radix-select, THEN
//   recompute the 45 selected Q rows (48x64x512 MFMA GEMM) and store
//   pre-scaled fp16 selQ[bh][48][64].
// Blocks [32,64): outbase partial: outbase[b] += bo (ks==0) + k-slice
//   of mean_flat[b] @ Wo  (b = idx>>3, ks = (idx&7)>>1, d-half = idx&1).
// ---------------------------------------------------------------------------
__global__ __launch_bounds__(256) void topk_kernel(
    const float* __restrict__ sparsity, int* __restrict__ topidx,
    const float* __restrict__ vsum, const float* __restrict__ Wo,
    const float* __restrict__ bo, float* __restrict__ outbase,
    const ushortT* __restrict__ Xf, const ushortT* __restrict__ WqT,
    const float* __restrict__ bq, ushortT* __restrict__ selQ)
{
    __shared__ __align__(16) char smem[49920];
    unsigned* vals        = (unsigned*)smem;                    // 32KB
    unsigned (*hist)[256] = (unsigned (*)[256])(smem + 32768);  // 8KB
    int* ssum             = (int*)(smem + 40960);               // 1KB
    int* eqidx            = (int*)(smem + 41984);               // 256B
    ushortT* selX         = (ushortT*)smem;                     // phase 2: 49,920B
    __shared__ unsigned prefix_s;
    __shared__ int need_s;
    __shared__ int cnt_gt_s, cnt_eq_s;
    const int tid = threadIdx.x;

    if (blockIdx.x >= 32) {
        const int idx = blockIdx.x - 32;
        const int b = idx >> 3, ks = (idx & 7) >> 1, dh = idx & 1;
        const int d = dh * 256 + tid;
        float acc = (ks == 0) ? bo[d] : 0.f;
        const int r0 = ks * 128;
        for (int r = r0; r < r0 + 128; ++r) {
            float mv = vsum[b * 512 + r] * (1.0f / S_);
            acc = fmaf(mv, Wo[(size_t)r * 512 + d], acc);
        }
        atomicAdd(&outbase[b * 512 + d], acc);
        return;
    }

    const int bh = blockIdx.x;
    const unsigned* sp = (const unsigned*)(sparsity + (size_t)bh * S_);
    for (int i = tid; i < S_; i += 256) vals[i] = sp[i];

    unsigned prefix = 0;
    int need = U_;
    const int rep = tid & 7;
    for (int level = 0; level < 4; ++level) {
        const int shift = 24 - level * 8;
#pragma unroll
        for (int r = 0; r < 8; ++r) hist[r][tid] = 0;
        __syncthreads();
        const unsigned pmask = (level == 0) ? 0u : (0xFFFFFFFFu << (shift + 8));
        for (int i = tid; i < S_; i += 256) {
            unsigned v = vals[i];
            if ((v & pmask) == prefix)
                atomicAdd(&hist[rep][(v >> shift) & 255], 1u);
        }
        __syncthreads();
        int bs = 0;
#pragma unroll
        for (int r = 0; r < 8; ++r) bs += (int)hist[r][tid];
        ssum[tid] = bs;
        __syncthreads();
        for (int off = 1; off < 256; off <<= 1) {
            int add = (tid + off < 256) ? ssum[tid + off] : 0;
            __syncthreads();
            ssum[tid] += add;
            __syncthreads();
        }
        int snext = (tid == 255) ? 0 : ssum[tid + 1];
        if (ssum[tid] >= need && snext < need) {
            prefix_s = prefix | ((unsigned)tid << shift);
            need_s = need - snext;
        }
        __syncthreads();
        prefix = prefix_s;
        need = need_s;
        __syncthreads();
    }
    const unsigned T = prefix;
    if (tid == 0) { cnt_gt_s = 0; cnt_eq_s = 0; }
    __syncthreads();
    for (int i = tid; i < S_; i += 256) {
        unsigned v = vals[i];
        if (v > T) {
            int p = atomicAdd(&cnt_gt_s, 1);
            topidx[bh * U_ + p] = i;
        } else if (v == T) {
            int p = atomicAdd(&cnt_eq_s, 1);
            if (p < 64) eqidx[p] = i;
        }
    }
    __syncthreads();
    if (tid == 0) {
        int rem = U_ - cnt_gt_s;
        int n = cnt_eq_s < 64 ? cnt_eq_s : 64;
        for (int a = 0; a < rem; ++a) {     // smallest indices among ties
            int best = 1 << 30, bj = 0;
            for (int j = 0; j < n; ++j)
                if (eqidx[j] < best) { best = eqidx[j]; bj = j; }
            topidx[bh * U_ + cnt_gt_s + a] = best;
            eqidx[bj] = 1 << 30;
        }
    }
    __syncthreads();               // topidx final; region A free for reuse

    // ---- phase 2: selQ = (Xf[sel] @ WqT^T + bq) * 0.125, fp16 ----
    const int b = bh >> 3, h = bh & 7;
    for (int i = tid; i < 48 * 64; i += 256) {
        const int row = i >> 6, ch = i & 63;
        half8 v;
#pragma unroll
        for (int z = 0; z < 8; ++z) v[z] = (_Float16)0.0f;
        if (row < U_) {
            const int s = topidx[bh * U_ + row];
            v = *(const half8*)&Xf[((size_t)b * 8192 + s) * 512 + ch * 8];
        }
        *(half8*)&selX[row * 520 + ch * 8] = v;
    }
    __syncthreads();

    const int w = tid >> 6, lane = tid & 63;
    const int quad = lane >> 4, c16 = lane & 15;
    f32x4 qacc[3];
#pragma unroll
    for (int mt = 0; mt < 3; ++mt) qacc[mt] = (f32x4){0.f, 0.f, 0.f, 0.f};
    const ushortT* brow = WqT + (size_t)(h * 64 + w * 16 + c16) * 512;
    for (int k0 = 0; k0 < 512; k0 += 32) {
        half8 bf = *(const half8*)&brow[k0 + quad * 8];
#pragma unroll
        for (int mt = 0; mt < 3; ++mt) {
            half8 af = *(const half8*)&selX[(mt * 16 + c16) * 520 + k0 + quad * 8];
            qacc[mt] = __builtin_amdgcn_mfma_f32_16x16x32_f16(af, bf, qacc[mt], 0, 0, 0);
        }
    }
    const float bb = bq[h * 64 + w * 16 + c16];
    ushortT* oq = selQ + (size_t)bh * 48 * 64 + (w * 16 + c16);
#pragma unroll
    for (int mt = 0; mt < 3; ++mt)
#pragma unroll
        for (int r = 0; r < 4; ++r) {
            const int m = mt * 16 + quad * 4 + r;
            float v = (m < U_) ? (qacc[mt][r] + bb) * 0.125f : 0.f;
            oq[(size_t)m * 64] = f2h(v);
        }
}

// ---------------------------------------------------------------------------
// MFMA attention partials (fp16), no-max softmax (|s| bounded ~4).
// Grid (NCHUNK=32, 32 bh), 256 thr.  Block = 256 keys, 2 chunks of 128.
// (R14: NCHUNK 16->32 — 1024 blocks = 4/CU for the latency-bound kernel.)
// Q fragments loaded directly from selQ (pre-scaled, L2-hot, 6KB/bh).
// ---------------------------------------------------------------------------
__global__ __launch_bounds__(256, 2) void attn_mfma(
    const ushortT* __restrict__ selQ, const ushortT* __restrict__ Kbuf,
    const ushortT* __restrict__ VT,
    float* __restrict__ pl, float* __restrict__ pacc)
{
    __shared__ float sc[48 * 132];          // scores f32; P fp16 in-place

    const int tid = threadIdx.x;
    const int w = tid >> 6, lane = tid & 63;
    const int quad = lane >> 4, c16 = lane & 15;
    const int bh = blockIdx.y;
    const int s_base = blockIdx.x * (S_ / NCHUNK);

    f32x4 O[3];
#pragma unroll
    for (int mt = 0; mt < 3; ++mt) O[mt] = (f32x4){0.f, 0.f, 0.f, 0.f};
    float lacc[12];
#pragma unroll
    for (int qi = 0; qi < 12; ++qi) lacc[qi] = 0.f;

    const ushortT* sq = selQ + (size_t)bh * 48 * 64;
    half8 qa[3][2];
#pragma unroll
    for (int mt = 0; mt < 3; ++mt)
#pragma unroll
        for (int kk = 0; kk < 2; ++kk)
            qa[mt][kk] = *(const half8*)&sq[(mt * 16 + c16) * 64 + kk * 32 + quad * 8];

    const ushortT* kb  = Kbuf + (size_t)bh * 8192 * 64;
    const ushortT* vtb = VT + ((size_t)bh * 64 + w * 16 + c16) * 8192;

    for (int ci = 0; ci < (S_ / NCHUNK) / 128; ++ci) {
        const int s0 = s_base + ci * 128;

        half8 kf[2][2];
#pragma unroll
        for (int nt2 = 0; nt2 < 2; ++nt2)
#pragma unroll
            for (int kk = 0; kk < 2; ++kk)
                kf[nt2][kk] = *(const half8*)&kb[
                    (size_t)(s0 + w * 32 + nt2 * 16 + c16) * 64 + kk * 32 + quad * 8];
        f32x4 sacc[3][2];
#pragma unroll
        for (int mt = 0; mt < 3; ++mt)
#pragma unroll
            for (int nt2 = 0; nt2 < 2; ++nt2) {
                sacc[mt][nt2] = (f32x4){0.f, 0.f, 0.f, 0.f};
#pragma unroll
                for (int kk = 0; kk < 2; ++kk)
                    sacc[mt][nt2] = __builtin_amdgcn_mfma_f32_16x16x32_f16(
                        qa[mt][kk], kf[nt2][kk], sacc[mt][nt2], 0, 0, 0);
            }
#pragma unroll
        for (int mt = 0; mt < 3; ++mt)
#pragma unroll
            for (int nt2 = 0; nt2 < 2; ++nt2)
#pragma unroll
                for (int r = 0; r < 4; ++r)
                    sc[(mt * 16 + quad * 4 + r) * 132 + w * 32 + nt2 * 16 + c16] =
                        sacc[mt][nt2][r];
        __syncthreads();

        half8 vb[4];
#pragma unroll
        for (int kk = 0; kk < 4; ++kk)
            vb[kk] = *(const half8*)&vtb[s0 + kk * 32 + quad * 8];

#pragma unroll
        for (int qi = 0; qi < 12; ++qi) {
            const int q = w * 12 + qi;
            float x0 = sc[q * 132 + lane];
            float x1 = sc[q * 132 + 64 + lane];
            ushortT u0 = f2h(__expf(x0));
            ushortT u1 = f2h(__expf(x1));
            lacc[qi] += h2f(u0) + h2f(u1);
            ushortT* pr = (ushortT*)&sc[q * 132];
            pr[lane] = u0;
            pr[lane + 64] = u1;
        }
        __syncthreads();

#pragma unroll
        for (int mt = 0; mt < 3; ++mt)
#pragma unroll
            for (int kk = 0; kk < 4; ++kk) {
                half8 pa = *(const half8*)((const ushortT*)sc +
                    (size_t)(mt * 16 + c16) * 264 + kk * 32 + quad * 8);
                O[mt] = __builtin_amdgcn_mfma_f32_16x16x32_f16(pa, vb[kk], O[mt], 0, 0, 0);
            }
        __syncthreads();
    }

#pragma unroll
    for (int mt = 0; mt < 3; ++mt)
#pragma unroll
        for (int r = 0; r < 4; ++r) {
            const int q = mt * 16 + quad * 4 + r;
            if (q < U_)
                pacc[(((size_t)bh * NCHUNK + blockIdx.x) * U_ + q) * 64 + w * 16 + c16] =
                    O[mt][r];
        }
#pragma unroll
    for (int qi = 0; qi < 12; ++qi) {
        const int q = w * 12 + qi;
        float ssum = lacc[qi];
#pragma unroll
        for (int off = 1; off < 64; off <<= 1) ssum += __shfl_xor(ssum, off);
        if (lane == 0 && q < U_)
            pl[((size_t)bh * NCHUNK + blockIdx.x) * U_ + q] = ssum;
    }
}

// ---------------------------------------------------------------------------
// Broadcast fill: out[b,s,:] = out_base[b,:]  (standalone again — R13's
// merge into attn inherited attn's 25KB LDS allocation and regressed ~10us;
// a 64MB BW-bound broadcast needs its own full-occupancy launch.)
// ---------------------------------------------------------------------------
__global__ __launch_bounds__(256) void fill_kernel(
    const float* __restrict__ outbase, float* __restrict__ out)
{
    size_t gid = (size_t)blockIdx.x * 256 + threadIdx.x;
    size_t e0 = gid * 4;
    int b = (int)(e0 >> 22);          // 8192*512 = 2^22
    int col = (int)(e0 & 511);
    float4 v = *(const float4*)&outbase[b * 512 + col];
    *(float4*)&out[e0] = v;
}

// ---------------------------------------------------------------------------
// Merged combine + correction: block (q, bh).
// ---------------------------------------------------------------------------
__global__ __launch_bounds__(512) void corr_out_kernel(
    const float* __restrict__ pl, const float* __restrict__ pacc,
    const float* __restrict__ vsum, const float* __restrict__ Wo,
    const int* __restrict__ topidx, float* __restrict__ out)
{
    __shared__ float corrS[64];
    const int q = blockIdx.x, bh = blockIdx.y;
    const int b = bh >> 3, h = bh & 7, tid = threadIdx.x;
    if (tid < 64) {
        float L = 0.f, a = 0.f;
        for (int c = 0; c < NCHUNK; ++c) {
            L += pl[((size_t)bh * NCHUNK + c) * U_ + q];
            a += pacc[(((size_t)bh * NCHUNK + c) * U_ + q) * 64 + tid];
        }
        corrS[tid] = a / L - vsum[b * 512 + h * 64 + tid] * (1.0f / S_);
    }
    __syncthreads();
    const int s = topidx[bh * U_ + q];
    const int d = tid;
    float delta = 0.f;
#pragma unroll
    for (int r = 0; r < 64; ++r)
        delta = fmaf(corrS[r], Wo[(size_t)(h * 64 + r) * 512 + d], delta);
    atomicAdd(&out[((size_t)b * S_ + s) * 512 + d], delta);
}

// ---------------------------------------------------------------------------
extern "C" void kernel_launch(void* const* d_in, const int* in_sizes, int n_in,
                              void* d_out, int out_size, void* d_ws, size_t ws_size,
                              hipStream_t stream)
{
    const float* X  = (const float*)d_in[0];
    const float* Wq = (const float*)d_in[1];
    const float* bq = (const float*)d_in[2];
    const float* Wk = (const float*)d_in[3];
    const float* bk = (const float*)d_in[4];
    const float* Wv = (const float*)d_in[5];
    const float* bv = (const float*)d_in[6];
    const float* Wo = (const float*)d_in[7];
    const float* bo = (const float*)d_in[8];
    float* out = (float*)d_out;

    char* ws = (char*)d_ws;
    size_t off = 0;
    auto alloc = [&](size_t bytes) {
        void* p = ws + off;
        off = (off + bytes + 255) & ~(size_t)255;
        return p;
    };
    ushortT* Xf   = (ushortT*)alloc((size_t)B_ * S_ * D_ * 2);
    ushortT* Kbuf = (ushortT*)alloc((size_t)B_ * S_ * D_ * 2);
    ushortT* VT   = (ushortT*)alloc((size_t)B_ * S_ * D_ * 2);
    ushortT* WqT  = (ushortT*)alloc((size_t)D_ * D_ * 2);
    ushortT* WkT  = (ushortT*)alloc((size_t)D_ * D_ * 2);
    ushortT* WvT  = (ushortT*)alloc((size_t)D_ * D_ * 2);
    ushortT* selQ = (ushortT*)alloc((size_t)B_ * H_ * 48 * 64 * 2);
    float* sparsity = (float*)alloc((size_t)B_ * H_ * S_ * 4);
    int*   topidx   = (int*)alloc((size_t)B_ * H_ * U_ * 4);
    float* pl       = (float*)alloc((size_t)B_ * H_ * NCHUNK * U_ * 4);
    float* pacc     = (float*)alloc((size_t)B_ * H_ * NCHUNK * U_ * 64 * 4);
    float* vsum     = (float*)alloc((size_t)B_ * 512 * 4);
    float* outbase  = (float*)alloc((size_t)B_ * 512 * 4);

    prep_kernel<<<8960, 256, 0, stream>>>(X, Xf, Wq, Wk, Wv, WqT, WkT, WvT,
                                          vsum, outbase);
    qkv_mfma<<<dim3(256, 6), 512, 0, stream>>>(Xf, WqT, WkT, WvT,
                                               bq, bk, bv, Kbuf, VT,
                                               sparsity, vsum);
    topk_kernel<<<64, 256, 0, stream>>>(sparsity, topidx, vsum, Wo, bo, outbase,
                                        Xf, WqT, bq, selQ);
    attn_mfma<<<dim3(NCHUNK, B_ * H_), 256, 0, stream>>>(selQ, Kbuf, VT,
                                                         pl, pacc);
    fill_kernel<<<(B_ * S_ * D_ / 4 + 255) / 256, 256, 0, stream>>>(outbase, out);
    corr_out_kernel<<<dim3(U_, B_ * H_), 512, 0, stream>>>(pl, pacc, vsum, Wo,
                                                           topidx, out);
}